// Round 1
// baseline (178.301 us; speedup 1.0000x reference)
//
#include <hip/hip_runtime.h>
#include <math.h>

// ---------------- workspace layout (float offsets) ----------------
// Only the first 16 tokens per batch matter (E = HEAD = 16 slices the T axis).
// 64 "real" rows total (b*16+t), everything else in the output is just bo.
#define WS_XN    0          // 64*1024                  LN'd x rows
#define WS_QKVP  65536      // 8 * 64*3072              split-K partials of q|k|v
#define WS_DIFF  1638400    // 1                        sum |ai1-ai0|
#define WS_AI1   1638404    // 64*1024                  iter-1 attention out (b*16+t, h*64+d)
#define WS_AI2   1703940    // 64*1024                  iter-2 attention out
#define WS_WOP   1769476    // 8 * 64*1024              split-K partials of ai_sel @ Wo^T
// end: 2293764 floats = ~9.2 MB

__device__ __forceinline__ float4 f4zero() { return make_float4(0.f, 0.f, 0.f, 0.f); }
__device__ __forceinline__ float4 f4add(float4 a, float4 b) {
    return make_float4(a.x + b.x, a.y + b.y, a.z + b.z, a.w + b.w);
}
__device__ __forceinline__ float4 f4fma(float s, float4 a, float4 c) {
    return make_float4(fmaf(s, a.x, c.x), fmaf(s, a.y, c.y),
                       fmaf(s, a.z, c.z), fmaf(s, a.w, c.w));
}
__device__ __forceinline__ float dot4acc(float4 a, float4 b, float acc) {
    acc = fmaf(a.x, b.x, acc); acc = fmaf(a.y, b.y, acc);
    acc = fmaf(a.z, b.z, acc); acc = fmaf(a.w, b.w, acc);
    return acc;
}

// ---------------- K1: LayerNorm of the 64 relevant rows ----------------
__global__ __launch_bounds__(256) void k_ln(const float* __restrict__ x,
                                            const float* __restrict__ lna,
                                            float* __restrict__ xn,
                                            float* __restrict__ diffg) {
    int r = blockIdx.x;                 // 0..63 = b*16 + t
    int b = r >> 4, t = r & 15;
    if (blockIdx.x == 0 && threadIdx.x == 0) diffg[0] = 0.f;   // zero diff accumulator
    const float* row = x + (size_t)(b * 2048 + t) * 1024;
    int tid = threadIdx.x;
    float4 xv = *(const float4*)&row[tid * 4];
    float s1 = xv.x + xv.y + xv.z + xv.w;
    float s2 = xv.x * xv.x + xv.y * xv.y + xv.z * xv.z + xv.w * xv.w;
    for (int off = 32; off; off >>= 1) {
        s1 += __shfl_xor(s1, off);
        s2 += __shfl_xor(s2, off);
    }
    __shared__ float ssum[4], ssq[4];
    int wv = tid >> 6, lane = tid & 63;
    if (lane == 0) { ssum[wv] = s1; ssq[wv] = s2; }
    __syncthreads();
    float tot = ssum[0] + ssum[1] + ssum[2] + ssum[3];
    float tq  = ssq[0] + ssq[1] + ssq[2] + ssq[3];
    float m   = tot * (1.0f / 1024.0f);
    float var = tq * (1.0f / 1024.0f) - m * m;
    float rs  = rsqrtf(var + 1e-5f);
    float4 w4 = *(const float4*)&lna[tid * 4];
    float4 o  = make_float4((xv.x - m) * rs * w4.x, (xv.y - m) * rs * w4.y,
                            (xv.z - m) * rs * w4.z, (xv.w - m) * rs * w4.w);
    *(float4*)&xn[r * 1024 + tid * 4] = o;
}

// ---------------- K2: q|k|v = xn @ [Wq|Wk|Wv]^T, split-K partials ----------------
// grid (96, 8): 96 tiles of 32 cols over 3072; 8 K-slices of 128.
__global__ __launch_bounds__(256) void k_qkv(const float* __restrict__ xn,
                                             const float* __restrict__ Wq,
                                             const float* __restrict__ Wk,
                                             const float* __restrict__ Wv,
                                             float* __restrict__ qkvp) {
    int ct  = blockIdx.x;               // 0..95
    int ksl = blockIdx.y;               // 0..7
    int m   = ct >> 5;
    const float* W = (m == 0) ? Wq : (m == 1) ? Wk : Wv;
    int j0 = (ct & 31) * 32;            // W row base
    int k0 = ksl * 128;
    __shared__ float At[64][132];       // pad: row stride 132 words -> 2-way banks
    __shared__ float Bt[32][132];
    int tid = threadIdx.x;
    for (int i = tid; i < 2048; i += 256) {
        int r = i >> 5, kk = (i & 31) << 2;
        *(float4*)&At[r][kk] = *(const float4*)&xn[r * 1024 + k0 + kk];
    }
    for (int i = tid; i < 1024; i += 256) {
        int r = i >> 5, kk = (i & 31) << 2;
        *(float4*)&Bt[r][kk] = *(const float4*)&W[(size_t)(j0 + r) * 1024 + k0 + kk];
    }
    __syncthreads();
    int rg = tid >> 4, cg = tid & 15;   // 4 rows x 2 cols per thread
    float acc[4][2];
#pragma unroll
    for (int i = 0; i < 4; i++) { acc[i][0] = 0.f; acc[i][1] = 0.f; }
    for (int k = 0; k < 128; k += 4) {
        float4 b0 = *(float4*)&Bt[cg * 2 + 0][k];
        float4 b1 = *(float4*)&Bt[cg * 2 + 1][k];
#pragma unroll
        for (int i = 0; i < 4; i++) {
            float4 a = *(float4*)&At[rg * 4 + i][k];
            acc[i][0] = dot4acc(a, b0, acc[i][0]);
            acc[i][1] = dot4acc(a, b1, acc[i][1]);
        }
    }
    float* dst = qkvp + (size_t)ksl * 196608;
    int colg = ct * 32 + cg * 2;
#pragma unroll
    for (int i = 0; i < 4; i++) {
        *(float2*)&dst[(rg * 4 + i) * 3072 + colg] = make_float2(acc[i][0], acc[i][1]);
    }
}

// ---------------- K3: the 3-iteration loop, one block per (b,h) ----------------
__global__ __launch_bounds__(256) void k_iter(
        const float* __restrict__ qkvp,
        const float* __restrict__ bq,  const float* __restrict__ bv,
        const float* __restrict__ lnc, const float* __restrict__ lnd,
        const float* __restrict__ Wlq, const float* __restrict__ blq,
        const float* __restrict__ Wlk, const float* __restrict__ blk_,
        const float* __restrict__ Wlv, const float* __restrict__ blv,
        const float* __restrict__ temp,
        float* __restrict__ ai1g, float* __restrict__ ai2g,
        float* __restrict__ diffg) {
    // LDS budget: 32768 (WA+WB) + 6*4352 (tiles) + 1088 (pS) + 16 = 59984 B < 64 KB
    __shared__ float WA[4096];          // time-shared: WlqT (phase A) / WlvT (phase D)
    __shared__ float WB[4096];          // WlkT (resident)
    __shared__ float inq[16 * 68], ink[16 * 68], inv[16 * 68];   // qcur,kcur,vcur (16x64, ld 68)
    __shared__ float qlS[16 * 68], klS[16 * 68], vlS[16 * 68];   // ql/qs, kl/ks, vl
    __shared__ float pS[16 * 17];
    __shared__ float dred[4];

    int tid  = threadIdx.x;
    int b    = blockIdx.x >> 4, h = blockIdx.x & 15;
    int t    = tid >> 4, dg = tid & 15;         // element owner: row t, cols dg*4..dg*4+3
    int lane = tid & 63, wv = tid >> 6;
    int rowi = b * 16 + t;
    int col  = h * 64 + dg * 4;

    // WB = Wlk^T (transposed so phase-A reads are [k][d] float4, 2-way banks)
    for (int i = tid; i < 4096; i += 256) {
        int d = i >> 6, k = i & 63;
        WB[k * 64 + d] = Wlk[i];
    }

    // fold the 8 split-K partials; apply scale/bias per the reference
    const float SCALE = 0.35355339059327378f;   // 64^-0.25
    float4 q4 = f4zero(), k4 = f4zero(), v4 = f4zero();
#pragma unroll
    for (int s = 0; s < 8; s++) {
        const float* P = qkvp + (size_t)s * 196608 + rowi * 3072 + col;
        q4 = f4add(q4, *(const float4*)&P[0]);
        k4 = f4add(k4, *(const float4*)&P[1024]);
        v4 = f4add(v4, *(const float4*)&P[2048]);
    }
    float4 bq4 = *(const float4*)&bq[col];
    float4 bv4 = *(const float4*)&bv[col];
    *(float4*)&inq[t * 68 + dg * 4] = make_float4(
        (q4.x + bq4.x) * SCALE, (q4.y + bq4.y) * SCALE,
        (q4.z + bq4.z) * SCALE, (q4.w + bq4.w) * SCALE);
    *(float4*)&ink[t * 68 + dg * 4] = make_float4(
        k4.x * SCALE, k4.y * SCALE, k4.z * SCALE, k4.w * SCALE);
    *(float4*)&inv[t * 68 + dg * 4] = f4add(v4, bv4);

    float4 blq4 = *(const float4*)&blq[dg * 4];
    float4 blk4 = *(const float4*)&blk_[dg * 4];
    float4 blv4 = *(const float4*)&blv[dg * 4];
    float lcw = lnc[lane], ldw = lnd[lane];
    float tempv = temp[0];

    float4 ai0 = f4zero(), ai1r = f4zero();
    float dlocal = 0.f;
    (void)ai1r;

    for (int it = 0; it < 3; ++it) {
        float t_it = tempv + 0.005f * (float)it;
        float tsc  = (t_it != 1.0f && t_it > 0.0f) ? rsqrtf(t_it) : 1.0f;

        // reload WA = Wlq^T (WA held WlvT at end of previous iteration)
        for (int i = tid; i < 4096; i += 256) {
            int d = i >> 6, k = i & 63;
            WA[k * 64 + d] = Wlq[i];
        }
        __syncthreads();   // WA ready; prev-iter state updates visible

        // -------- Phase A: ql = qcur@Wlq^T+blq ; kl = kcur@Wlk^T+blk --------
        float4 aq = f4zero(), ak = f4zero();
        for (int k = 0; k < 64; ++k) {
            float qi = inq[t * 68 + k];            // wave-broadcast
            float ki = ink[t * 68 + k];
            aq = f4fma(qi, *(float4*)&WA[k * 64 + dg * 4], aq);
            ak = f4fma(ki, *(float4*)&WB[k * 64 + dg * 4], ak);
        }
        aq = f4add(aq, blq4);
        ak = f4add(ak, blk4);
        *(float4*)&qlS[t * 68 + dg * 4] = aq;
        *(float4*)&klS[t * 68 + dg * 4] = ak;
        __syncthreads();

        // -------- Phase B: LN rows (wave-shuffle), overlap WA <- Wlv^T --------
        for (int i = tid; i < 4096; i += 256) {
            int d = i >> 6, k = i & 63;
            WA[k * 64 + d] = Wlv[i];
        }
        float xq[4], xk[4], mq[4], rq[4], mk[4], rk[4];
#pragma unroll
        for (int s = 0; s < 4; ++s) {
            int tr = wv * 4 + s;
            xq[s] = qlS[tr * 68 + lane];
            xk[s] = klS[tr * 68 + lane];
            float s1q = xq[s], s2q = xq[s] * xq[s];
            float s1k = xk[s], s2k = xk[s] * xk[s];
            for (int off = 32; off; off >>= 1) {
                s1q += __shfl_xor(s1q, off); s2q += __shfl_xor(s2q, off);
                s1k += __shfl_xor(s1k, off); s2k += __shfl_xor(s2k, off);
            }
            mq[s] = s1q * (1.0f / 64.0f);
            float vq = s2q * (1.0f / 64.0f) - mq[s] * mq[s];
            rq[s] = rsqrtf(vq + 1e-5f);
            mk[s] = s1k * (1.0f / 64.0f);
            float vk = s2k * (1.0f / 64.0f) - mk[s] * mk[s];
            rk[s] = rsqrtf(vk + 1e-5f);
        }
        __syncthreads();   // all reads of qlS/klS done; WA(WlvT) complete
#pragma unroll
        for (int s = 0; s < 4; ++s) {
            int tr = wv * 4 + s;
            ink[tr * 68 + lane] = xk[s];   // kcur_next = kl (pre-LN), done early
            qlS[tr * 68 + lane] = (xq[s] - mq[s]) * rq[s] * lcw * tsc;   // qs
            klS[tr * 68 + lane] = (xk[s] - mk[s]) * rk[s] * ldw;         // ks
        }
        __syncthreads();

        // -------- Phase C: logits (16x16) + softmax; thread = (t, j=dg) --------
        float acc = 0.f;
        for (int d = 0; d < 64; ++d)
            acc += qlS[t * 68 + d] * klS[dg * 68 + d];
        float lg = acc * 0.125f;                 // sm_scale = 1/sqrt(64)
        float mx = lg;
        for (int off = 8; off; off >>= 1) mx = fmaxf(mx, __shfl_xor(mx, off));
        float e = expf(lg - mx);
        float sm = e;
        for (int off = 8; off; off >>= 1) sm += __shfl_xor(sm, off);
        pS[t * 17 + dg] = e / sm;
        __syncthreads();

        // -------- Phase D1: vl = vcur@Wlv^T + blv (WA holds WlvT) --------
        float4 av = f4zero();
        for (int k = 0; k < 64; ++k) {
            float vi = inv[t * 68 + k];
            av = f4fma(vi, *(float4*)&WA[k * 64 + dg * 4], av);
        }
        av = f4add(av, blv4);
        *(float4*)&vlS[t * 68 + dg * 4] = av;
        __syncthreads();

        // -------- Phase D2: ai = softmax(P) @ vl; bookkeeping --------
        float4 ai = f4zero();
#pragma unroll
        for (int jj = 0; jj < 16; ++jj)
            ai = f4fma(pS[t * 17 + jj], *(float4*)&vlS[jj * 68 + dg * 4], ai);

        if (it == 0) {
            ai0 = ai;
        } else if (it == 1) {
            dlocal = fabsf(ai.x - ai0.x) + fabsf(ai.y - ai0.y) +
                     fabsf(ai.z - ai0.z) + fabsf(ai.w - ai0.w);
            *(float4*)&ai1g[rowi * 1024 + col] = ai;
        } else {
            *(float4*)&ai2g[rowi * 1024 + col] = ai;
        }
        // qcur += ai ; vcur_next = vl (own values; ink already updated in B)
        float4 q0 = *(float4*)&inq[t * 68 + dg * 4];
        *(float4*)&inq[t * 68 + dg * 4] = f4add(q0, ai);
        *(float4*)&inv[t * 68 + dg * 4] = av;
        // next-iteration top __syncthreads() covers these writes
    }

    // block-reduce sum |ai1-ai0| -> global scalar
    float ds = dlocal;
    for (int off = 32; off; off >>= 1) ds += __shfl_xor(ds, off);
    if (lane == 0) dred[wv] = ds;
    __syncthreads();
    if (tid == 0) atomicAdd(diffg, dred[0] + dred[1] + dred[2] + dred[3]);
}

// ---------------- K4: ai_sel @ Wo^T, split-K partials ----------------
// grid (32, 8): 32 tiles of 32 cols over 1024; 8 K-slices of 128.
__global__ __launch_bounds__(256) void k_wo(const float* __restrict__ ai1g,
                                            const float* __restrict__ ai2g,
                                            const float* __restrict__ diffg,
                                            const float* __restrict__ thrp,
                                            const float* __restrict__ facp,
                                            const float* __restrict__ Wo,
                                            float* __restrict__ wop) {
    // done1 <=> diff1 < thr + fac*diff1  ->  attn_out = done1 ? ai1 : ai2
    float diff = diffg[0] * (1.0f / 8388608.0f);   // mean over B*H*T*hd
    const float* A = (diff < thrp[0] + facp[0] * diff) ? ai1g : ai2g;
    int jt  = blockIdx.x;               // 0..31
    int ksl = blockIdx.y;               // 0..7
    int k0  = ksl * 128;
    __shared__ float At[64][132];
    __shared__ float Bt[32][132];
    int tid = threadIdx.x;
    for (int i = tid; i < 2048; i += 256) {
        int r = i >> 5, kk = (i & 31) << 2;
        *(float4*)&At[r][kk] = *(const float4*)&A[r * 1024 + k0 + kk];
    }
    for (int i = tid; i < 1024; i += 256) {
        int r = i >> 5, kk = (i & 31) << 2;
        *(float4*)&Bt[r][kk] = *(const float4*)&Wo[(size_t)(jt * 32 + r) * 1024 + k0 + kk];
    }
    __syncthreads();
    int rg = tid >> 4, cg = tid & 15;
    float acc[4][2];
#pragma unroll
    for (int i = 0; i < 4; i++) { acc[i][0] = 0.f; acc[i][1] = 0.f; }
    for (int k = 0; k < 128; k += 4) {
        float4 b0 = *(float4*)&Bt[cg * 2 + 0][k];
        float4 b1 = *(float4*)&Bt[cg * 2 + 1][k];
#pragma unroll
        for (int i = 0; i < 4; i++) {
            float4 a = *(float4*)&At[rg * 4 + i][k];
            acc[i][0] = dot4acc(a, b0, acc[i][0]);
            acc[i][1] = dot4acc(a, b1, acc[i][1]);
        }
    }
    float* dst = wop + (size_t)ksl * 65536;
    int colg = jt * 32 + cg * 2;
#pragma unroll
    for (int i = 0; i < 4; i++) {
        *(float2*)&dst[(rg * 4 + i) * 1024 + colg] = make_float2(acc[i][0], acc[i][1]);
    }
}

// ---------------- K5: final output write (the 33.5 MB) ----------------
// out[b,t,:] = bo for t>=16 ; bo + sum_s wop[s] for the 64 real rows.
__global__ __launch_bounds__(256) void k_bo(const float* __restrict__ bo,
                                            const float* __restrict__ wop,
                                            float* __restrict__ out) {
    int row = blockIdx.x;               // 0..8191
    int tid = threadIdx.x;
    int b = row >> 11, t = row & 2047;
    float4 o = *(const float4*)&bo[tid * 4];
    if (t < 16) {                       // block-uniform branch
        int ri = b * 16 + t;
#pragma unroll
        for (int s = 0; s < 8; s++) {
            float4 p = *(const float4*)&wop[(size_t)s * 65536 + ri * 1024 + tid * 4];
            o = f4add(o, p);
        }
    }
    *(float4*)&out[(size_t)row * 1024 + tid * 4] = o;
}

extern "C" void kernel_launch(void* const* d_in, const int* in_sizes, int n_in,
                              void* d_out, int out_size, void* d_ws, size_t ws_size,
                              hipStream_t stream) {
    (void)in_sizes; (void)n_in; (void)out_size; (void)ws_size;
    const float* x    = (const float*)d_in[0];
    const float* Wq   = (const float*)d_in[1];
    const float* bq   = (const float*)d_in[2];
    const float* Wk   = (const float*)d_in[3];
    const float* Wv   = (const float*)d_in[4];
    const float* bv   = (const float*)d_in[5];
    const float* Wo   = (const float*)d_in[6];
    const float* bo   = (const float*)d_in[7];
    const float* lna  = (const float*)d_in[8];
    const float* lnc  = (const float*)d_in[9];
    const float* lnd  = (const float*)d_in[10];
    const float* Wlq  = (const float*)d_in[11];
    const float* blq  = (const float*)d_in[12];
    const float* Wlk  = (const float*)d_in[13];
    const float* blk_ = (const float*)d_in[14];
    const float* Wlv  = (const float*)d_in[15];
    const float* blv  = (const float*)d_in[16];
    const float* temp = (const float*)d_in[17];
    const float* thr  = (const float*)d_in[18];
    const float* fac  = (const float*)d_in[19];
    float* ws  = (float*)d_ws;
    float* out = (float*)d_out;

    k_ln  <<<64, 256, 0, stream>>>(x, lna, ws + WS_XN, ws + WS_DIFF);
    k_qkv <<<dim3(96, 8), 256, 0, stream>>>(ws + WS_XN, Wq, Wk, Wv, ws + WS_QKVP);
    k_iter<<<64, 256, 0, stream>>>(ws + WS_QKVP, bq, bv, lnc, lnd,
                                   Wlq, blq, Wlk, blk_, Wlv, blv, temp,
                                   ws + WS_AI1, ws + WS_AI2, ws + WS_DIFF);
    k_wo  <<<dim3(32, 8), 256, 0, stream>>>(ws + WS_AI1, ws + WS_AI2, ws + WS_DIFF,
                                            thr, fac, Wo, ws + WS_WOP);
    k_bo  <<<8192, 256, 0, stream>>>(bo, ws + WS_WOP, out);
}